// Round 7
// baseline (1046.749 us; speedup 1.0000x reference)
//
#include <hip/hip_runtime.h>
#include <hip/hip_bf16.h>

// Problem constants (fixed by setup_inputs)
#define D     128
#define NLIT  32000
#define NCLA  64000
#define KLIT  3
#define NEDGE 192000
#define BGR   32
#define ITERS 4
#define LITS_PER_GRAPH 1000

typedef _Float16 f16x8 __attribute__((ext_vector_type(8)));
typedef float    f32x4 __attribute__((ext_vector_type(4)));

#define TSTRIDE 40   // LDS A-tile row stride in f16 (80 B): b128 reads at bank floor

__device__ __forceinline__ float sigf(float x)  { return 1.f / (1.f + __expf(-x)); }
__device__ __forceinline__ float tanhft(float x){ return 1.f - 2.f / (__expf(2.f * x) + 1.f); }

// ---------------------------------------------------------------------------
// one-time conversions
// ---------------------------------------------------------------------------
__global__ void conv_x_kernel(const float* __restrict__ x, _Float16* __restrict__ o) {
    int t = blockIdx.x * blockDim.x + threadIdx.x;          // NLIT*16
    if (t >= NLIT * 16) return;
    const float* p = x + t * 8;
    f16x8 v;
#pragma unroll
    for (int i = 0; i < 8; ++i) v[i] = (_Float16)p[i];
    *(f16x8*)((_Float16*)o + t * 8) = v;
}

// Wc: 512 x 256 f16  ([n][k], k<128 from Wih, else Whh)
__global__ void conv_wc_kernel(const float* __restrict__ Wih,
                               const float* __restrict__ Whh,
                               _Float16* __restrict__ Wc) {
    int n = blockIdx.x, k = threadIdx.x;                    // 512 x 256
    float v = (k < 128) ? Wih[n * 128 + k] : Whh[n * 128 + k - 128];
    Wc[n * 256 + k] = (_Float16)v;
}

// Wl: 512 x 384 f16  ([n][k], k<256 from Wih, else Whh)
__global__ void conv_wl_kernel(const float* __restrict__ Wih,
                               const float* __restrict__ Whh,
                               _Float16* __restrict__ Wl) {
    int n = blockIdx.x, k = threadIdx.x;                    // 512 x 384
    float v = (k < 256) ? Wih[n * 256 + k] : Whh[n * 128 + k - 256];
    Wl[n * 384 + k] = (_Float16)v;
}

// bias combine + hc0 (= C_w + C_b as f16, the iter-0 h_c broadcast row)
__global__ void conv_bias_kernel(const float* bih_c, const float* bhh_c, float* bc,
                                 const float* bih_l, const float* bhh_l, float* bl,
                                 const float* C_w, const float* C_b,
                                 _Float16* hc0g) {
    int t = threadIdx.x;                                    // 512
    bc[t] = bih_c[t] + bhh_c[t];
    bl[t] = bih_l[t] + bhh_l[t];
    if (t < 128) hc0g[t] = (_Float16)(C_w[t] + C_b[t]);
}

// ---------------------------------------------------------------------------
// CSR build: counts -> (block sums -> scan -> block-local scan) -> fill
// ---------------------------------------------------------------------------
__global__ void count_edges_kernel(const int* __restrict__ lit_idx,
                                   int* __restrict__ counts) {
    int e = blockIdx.x * blockDim.x + threadIdx.x;
    if (e < NEDGE) atomicAdd(&counts[lit_idx[e]], 1);
}

__global__ __launch_bounds__(256)
void block_sum_kernel(const int* __restrict__ counts, int* __restrict__ bsum) {
    int b = blockIdx.x, t = threadIdx.x;
    int v = counts[b * 256 + t];
    int lane = t & 63, w = t >> 6;
#pragma unroll
    for (int off = 32; off > 0; off >>= 1) v += __shfl_down(v, off, 64);
    __shared__ int ws[4];
    if (lane == 0) ws[w] = v;
    __syncthreads();
    if (t == 0) bsum[b] = ws[0] + ws[1] + ws[2] + ws[3];
}

__global__ void scan_bsum_kernel(const int* __restrict__ bsum,
                                 int* __restrict__ ebsum,
                                 int* __restrict__ starts) {
    __shared__ int s[128];
    int t = threadIdx.x;
    int v = (t < 125) ? bsum[t] : 0;
    s[t] = v;
    __syncthreads();
    for (int off = 1; off < 128; off <<= 1) {
        int y = (t >= off) ? s[t - off] : 0;
        __syncthreads();
        s[t] += y;
        __syncthreads();
    }
    if (t < 125) ebsum[t] = s[t] - v;       // exclusive
    if (t == 0) starts[NLIT] = NEDGE;
}

__global__ __launch_bounds__(256)
void scan_write_kernel(const int* __restrict__ counts,
                       const int* __restrict__ ebsum,
                       int* __restrict__ starts,
                       int* __restrict__ cursor) {
    int b = blockIdx.x, t = threadIdx.x;
    int idx = b * 256 + t;
    int v = counts[idx];
    int lane = t & 63, w = t >> 6;
    int x = v;
#pragma unroll
    for (int off = 1; off < 64; off <<= 1) {
        int y = __shfl_up(x, off, 64);
        if (lane >= off) x += y;
    }
    __shared__ int wsum[4];
    if (lane == 63) wsum[w] = x;
    __syncthreads();
    int woff = 0;
#pragma unroll
    for (int i = 0; i < 4; ++i) if (i < w) woff += wsum[i];
    int g = ebsum[b] + woff + x - v;        // exclusive prefix
    starts[idx] = g;
    cursor[idx] = g;
}

__global__ void fill_csr_kernel(const int* __restrict__ lit_idx,
                                const int* __restrict__ clause_idx,
                                int* __restrict__ cursor,
                                int* __restrict__ edge_clause) {
    int e = blockIdx.x * blockDim.x + threadIdx.x;
    if (e < NEDGE) {
        int l = lit_idx[e];
        int pos = atomicAdd(&cursor[l], 1);
        edge_clause[pos] = clause_idx[e];
    }
}

// ---------------------------------------------------------------------------
// msg_l[l][:] = sum over clauses of literal l of h_c16[clause][:]  (f16 io, fp32 acc)
// high-occupancy streaming gather (separate kernel — round-5 fusion regressed)
// ---------------------------------------------------------------------------
__global__ void gather_msg_kernel(const _Float16* __restrict__ h_c16,
                                  _Float16* __restrict__ msg16,
                                  const int* __restrict__ starts,
                                  const int* __restrict__ edge_clause) {
    int t = blockIdx.x * blockDim.x + threadIdx.x;          // NLIT*16
    if (t >= NLIT * 16) return;
    int l = t >> 4;
    int off = (t & 15) * 8;
    int s = starts[l], e = starts[l + 1];
    float a[8];
#pragma unroll
    for (int i = 0; i < 8; ++i) a[i] = 0.f;
    for (int j = s; j < e; ++j) {
        f16x8 v = *(const f16x8*)&h_c16[(size_t)edge_clause[j] * D + off];
#pragma unroll
        for (int i = 0; i < 8; ++i) a[i] += (float)v[i];
    }
    f16x8 o;
#pragma unroll
    for (int i = 0; i < 8; ++i) o[i] = (_Float16)a[i];
    *(f16x8*)&msg16[(size_t)l * D + off] = o;
}

// ---------------------------------------------------------------------------
// Clause LSTM (MFMA): 128 rows/block, d-half per block (c = bx&1).
// A = [gather3(h_l) | h_c_old], K=256.
// A staged through LDS (cross-wave reuse); B fragments loaded DIRECTLY from
// global into registers (zero cross-wave reuse -> LDS round-trip wasted).
// Both register-prefetched one chunk ahead.
// ---------------------------------------------------------------------------
__global__ __launch_bounds__(256, 3)
void clause_mfma_kernel(const _Float16* __restrict__ h_l16,   // NLIT x 128
                        const _Float16* __restrict__ h_c_old, // NCLA x 128
                        _Float16* __restrict__ h_c_new,       // NCLA x 128
                        _Float16* __restrict__ c_c16,         // NCLA x 128 (f16 cell)
                        const _Float16* __restrict__ Wc,      // 512 x 256
                        const float* __restrict__ bc,         // 512
                        const _Float16* __restrict__ hc0g,    // 128 (iter-0 h_c row)
                        const int* __restrict__ lit_idx,
                        int first) {
    __shared__ _Float16 At[128 * TSTRIDE];
    __shared__ int      lidx[384];

    const int tid  = threadIdx.x;
    const int w    = tid >> 6;
    const int lane = tid & 63;
    const int qd   = lane >> 4;
    const int ln   = lane & 15;
    const int c    = blockIdx.x & 1;             // d-half: cols [64c, 64c+64)
    const int row0 = (blockIdx.x >> 1) * 128;

    for (int i = tid; i < 384; i += 256) lidx[i] = lit_idx[row0 * 3 + i];
    __syncthreads();                             // lidx visible before prefetch

    const int nrow = c * 64 + 16 * w + ln;       // W row base for this lane's col
    const int koff = qd * 8;                     // lane's k-granule inside chunk

    f16x8 ldB[4];    // B prefetch (direct global, per-gate)
    f16x8 ldG[2][3]; // A prefetch (ch<4: 3-lit gather; ch>=4: ldG[s2][0] = copy)

    // ---- prefetch ch 0
#pragma unroll
    for (int g = 0; g < 4; ++g)
        ldB[g] = *(const f16x8*)&Wc[(size_t)(g * 128 + nrow) * 256 + koff];
#pragma unroll
    for (int s2 = 0; s2 < 2; ++s2) {
        int s = tid + 256 * s2;
        int m = s >> 2, col8 = (s & 3) * 8;
#pragma unroll
        for (int r = 0; r < 3; ++r)
            ldG[s2][r] = *(const f16x8*)&h_l16[(size_t)lidx[3 * m + r] * D + col8];
    }

    f32x4 acc[8][4];
#pragma unroll
    for (int R = 0; R < 8; ++R)
#pragma unroll
        for (int g = 0; g < 4; ++g) { acc[R][g][0]=0.f; acc[R][g][1]=0.f; acc[R][g][2]=0.f; acc[R][g][3]=0.f; }

    for (int ch = 0; ch < 8; ++ch) {
        if (ch) __syncthreads();         // prev chunk's At reads complete
        // ---- A tile to LDS
#pragma unroll
        for (int s2 = 0; s2 < 2; ++s2) {
            int s = tid + 256 * s2;
            int m = s >> 2, col8 = (s & 3) * 8;
            if (ch < 4) {
                f16x8 o;
#pragma unroll
                for (int e = 0; e < 8; ++e)
                    o[e] = (_Float16)((float)ldG[s2][0][e] + (float)ldG[s2][1][e] + (float)ldG[s2][2][e]);
                *(f16x8*)&At[m * TSTRIDE + col8] = o;
            } else {
                *(f16x8*)&At[m * TSTRIDE + col8] = ldG[s2][0];
            }
        }
        // ---- current-chunk B fragments (already in regs)
        f16x8 bf[4];
#pragma unroll
        for (int g = 0; g < 4; ++g) bf[g] = ldB[g];
        // ---- prefetch ch+1 (latency overlapped with MFMA below)
        if (ch < 7) {
            const int k0n = (ch + 1) * 32;
#pragma unroll
            for (int g = 0; g < 4; ++g)
                ldB[g] = *(const f16x8*)&Wc[(size_t)(g * 128 + nrow) * 256 + k0n + koff];
            if (ch + 1 < 4) {
#pragma unroll
                for (int s2 = 0; s2 < 2; ++s2) {
                    int s = tid + 256 * s2;
                    int m = s >> 2, col8 = (s & 3) * 8;
#pragma unroll
                    for (int r = 0; r < 3; ++r)
                        ldG[s2][r] = *(const f16x8*)&h_l16[(size_t)lidx[3 * m + r] * D + k0n + col8];
                }
            } else {
                const int kk = k0n - 128;
#pragma unroll
                for (int s2 = 0; s2 < 2; ++s2) {
                    int s = tid + 256 * s2;
                    int m = s >> 2, col8 = (s & 3) * 8;
                    ldG[s2][0] = first ? *(const f16x8*)&hc0g[kk + col8]
                                       : *(const f16x8*)&h_c_old[(size_t)(row0 + m) * D + kk + col8];
                }
            }
        }
        __syncthreads();
        // ---- fragments + MFMA
        f16x8 af[8];
#pragma unroll
        for (int R = 0; R < 8; ++R)
            af[R] = *(const f16x8*)&At[(16 * R + ln) * TSTRIDE + koff];
#pragma unroll
        for (int R = 0; R < 8; ++R)
#pragma unroll
            for (int g = 0; g < 4; ++g)
                acc[R][g] = __builtin_amdgcn_mfma_f32_16x16x32_f16(af[R], bf[g], acc[R][g], 0, 0, 0);
    }

    // ---- fused LSTM epilogue (full i,f,g,o quadruple in registers; f16 cell)
    const int dcol = c * 64 + 16 * w + ln;     // 0..127
    const float b0 = bc[dcol], b1 = bc[128 + dcol], b2 = bc[256 + dcol], b3 = bc[384 + dcol];
#pragma unroll
    for (int R = 0; R < 8; ++R) {
#pragma unroll
        for (int r = 0; r < 4; ++r) {
            int m = row0 + 16 * R + qd * 4 + r;
            size_t idx = (size_t)m * D + dcol;
            float gi = acc[R][0][r] + b0;
            float gf = acc[R][1][r] + b1;
            float gg = acc[R][2][r] + b2;
            float go = acc[R][3][r] + b3;
            float cn = sigf(gi) * tanhft(gg);
            if (!first) cn += sigf(gf) * (float)c_c16[idx];
            float h  = sigf(go) * tanhft(cn);
            c_c16[idx]   = (_Float16)cn;
            h_c_new[idx] = (_Float16)h;
        }
    }
}

// ---------------------------------------------------------------------------
// Literal LSTM (MFMA): A = [msg_l | h_old[flip] | h_old], K=384, 128 rows/block.
// Same structure: A via LDS, B direct-global, both prefetched.
// ---------------------------------------------------------------------------
__global__ __launch_bounds__(256, 3)
void literal_mfma_kernel(const _Float16* __restrict__ h_old16, // NLIT x 128
                         const _Float16* __restrict__ msg16,   // NLIT x 128
                         _Float16* __restrict__ h_new16,       // NLIT x 128
                         float* __restrict__ h32,              // fp32 out (final iter)
                         _Float16* __restrict__ c_l16,         // NLIT x 128 (f16 cell)
                         const _Float16* __restrict__ Wl384,   // 512 x 384
                         const float* __restrict__ bl,         // 512
                         const int* __restrict__ flip_perm,
                         int first) {
    __shared__ _Float16 At[128 * TSTRIDE];
    __shared__ int      flip_s[128];

    const int tid  = threadIdx.x;
    const int w    = tid >> 6;
    const int lane = tid & 63;
    const int qd   = lane >> 4;
    const int ln   = lane & 15;
    const int c    = blockIdx.x & 1;
    const int row0 = (blockIdx.x >> 1) * 128;

    if (tid < 128) flip_s[tid] = flip_perm[row0 + tid];
    __syncthreads();

    const int nrow = c * 64 + 16 * w + ln;
    const int koff = qd * 8;

    f16x8 ldB[4];
    f16x8 ldA[2];

    // ---- prefetch ch 0 (msg)
#pragma unroll
    for (int g = 0; g < 4; ++g)
        ldB[g] = *(const f16x8*)&Wl384[(size_t)(g * 128 + nrow) * 384 + koff];
#pragma unroll
    for (int s2 = 0; s2 < 2; ++s2) {
        int s = tid + 256 * s2;
        int m = s >> 2, col8 = (s & 3) * 8;
        ldA[s2] = *(const f16x8*)&msg16[(size_t)(row0 + m) * D + col8];
    }

    f32x4 acc[8][4];
#pragma unroll
    for (int R = 0; R < 8; ++R)
#pragma unroll
        for (int g = 0; g < 4; ++g) { acc[R][g][0]=0.f; acc[R][g][1]=0.f; acc[R][g][2]=0.f; acc[R][g][3]=0.f; }

    for (int ch = 0; ch < 12; ++ch) {
        if (ch) __syncthreads();
        // ---- A tile to LDS
#pragma unroll
        for (int s2 = 0; s2 < 2; ++s2) {
            int s = tid + 256 * s2;
            int m = s >> 2, col8 = (s & 3) * 8;
            *(f16x8*)&At[m * TSTRIDE + col8] = ldA[s2];
        }
        // ---- current-chunk B fragments
        f16x8 bf[4];
#pragma unroll
        for (int g = 0; g < 4; ++g) bf[g] = ldB[g];
        // ---- prefetch ch+1
        if (ch < 11) {
            const int k0n = (ch + 1) * 32;
#pragma unroll
            for (int g = 0; g < 4; ++g)
                ldB[g] = *(const f16x8*)&Wl384[(size_t)(g * 128 + nrow) * 384 + k0n + koff];
#pragma unroll
            for (int s2 = 0; s2 < 2; ++s2) {
                int s = tid + 256 * s2;
                int m = s >> 2, col8 = (s & 3) * 8;
                const _Float16* g;
                if (k0n < 128)      g = msg16   + (size_t)(row0 + m) * D + k0n + col8;
                else if (k0n < 256) g = h_old16 + (size_t)flip_s[m] * D + (k0n - 128) + col8;
                else                g = h_old16 + (size_t)(row0 + m) * D + (k0n - 256) + col8;
                ldA[s2] = *(const f16x8*)g;
            }
        }
        __syncthreads();
        // ---- fragments + MFMA
        f16x8 af[8];
#pragma unroll
        for (int R = 0; R < 8; ++R)
            af[R] = *(const f16x8*)&At[(16 * R + ln) * TSTRIDE + koff];
#pragma unroll
        for (int R = 0; R < 8; ++R)
#pragma unroll
            for (int g = 0; g < 4; ++g)
                acc[R][g] = __builtin_amdgcn_mfma_f32_16x16x32_f16(af[R], bf[g], acc[R][g], 0, 0, 0);
    }

    const int dcol = c * 64 + 16 * w + ln;
    const float b0 = bl[dcol], b1 = bl[128 + dcol], b2 = bl[256 + dcol], b3 = bl[384 + dcol];
#pragma unroll
    for (int R = 0; R < 8; ++R) {
#pragma unroll
        for (int r = 0; r < 4; ++r) {
            int m = row0 + 16 * R + qd * 4 + r;
            size_t idx = (size_t)m * D + dcol;
            float gi = acc[R][0][r] + b0;
            float gf = acc[R][1][r] + b1;
            float gg = acc[R][2][r] + b2;
            float go = acc[R][3][r] + b3;
            float cn = sigf(gi) * tanhft(gg);
            if (!first) cn += sigf(gf) * (float)c_l16[idx];
            float h  = sigf(go) * tanhft(cn);
            c_l16[idx]   = (_Float16)cn;
            h_new16[idx] = (_Float16)h;
            if (h32) h32[idx] = h;
        }
    }
}

// ---------------------------------------------------------------------------
// votes stage 1: one wave per literal, no atomics.
// ---------------------------------------------------------------------------
__global__ __launch_bounds__(256)
void votes_stage1_kernel(const float* __restrict__ h_l,
                         const float* __restrict__ out_w,
                         const float* __restrict__ out_b,
                         float* __restrict__ votes_out) {
    int w    = threadIdx.x >> 6;            // wave in block
    int lane = threadIdx.x & 63;
    int l    = blockIdx.x * 4 + w;          // grid = NLIT/4
    if (l >= NLIT) return;
    const float2 v = *(const float2*)&h_l[(size_t)l * D + lane * 2];
    const float2 ww = *(const float2*)&out_w[lane * 2];
    float p = v.x * ww.x + v.y * ww.y;
#pragma unroll
    for (int off = 32; off > 0; off >>= 1) p += __shfl_down(p, off, 64);
    if (lane == 0) votes_out[l] = p + out_b[0];
}

// votes stage 2: one block per graph, sum 1000 contiguous votes -> mean
__global__ __launch_bounds__(256)
void votes_stage2_kernel(const float* __restrict__ votes,
                         float* __restrict__ out0) {
    int b = blockIdx.x;                     // 32 graphs
    int t = threadIdx.x;
    const float* base = votes + (size_t)b * LITS_PER_GRAPH;
    float s = 0.f;
    for (int i = t; i < LITS_PER_GRAPH; i += 256) s += base[i];
#pragma unroll
    for (int off = 32; off > 0; off >>= 1) s += __shfl_down(s, off, 64);
    __shared__ float ws[4];
    if ((t & 63) == 0) ws[t >> 6] = s;
    __syncthreads();
    if (t == 0) out0[b] = (ws[0] + ws[1] + ws[2] + ws[3]) / (float)LITS_PER_GRAPH;
}

// ---------------------------------------------------------------------------
extern "C" void kernel_launch(void* const* d_in, const int* in_sizes, int n_in,
                              void* d_out, int out_size, void* d_ws, size_t ws_size,
                              hipStream_t stream) {
    (void)in_sizes; (void)n_in; (void)out_size; (void)ws_size;

    const float* x_unk  = (const float*)d_in[0];
    const float* C_w    = (const float*)d_in[1];
    const float* C_b    = (const float*)d_in[2];
    const float* Wih_lc = (const float*)d_in[3];
    const float* Whh_lc = (const float*)d_in[4];
    const float* bih_lc = (const float*)d_in[5];
    const float* bhh_lc = (const float*)d_in[6];
    const float* Wih_cl = (const float*)d_in[7];
    const float* Whh_cl = (const float*)d_in[8];
    const float* bih_cl = (const float*)d_in[9];
    const float* bhh_cl = (const float*)d_in[10];
    const float* out_w  = (const float*)d_in[11];
    const float* out_b  = (const float*)d_in[12];
    const int* lit_idx    = (const int*)d_in[13];
    const int* clause_idx = (const int*)d_in[14];
    const int* flip_perm  = (const int*)d_in[16];

    // ---- workspace layout (bytes, 256-aligned chunks)
    char* W = (char*)d_ws;
    size_t off = 0;
    auto alloc = [&](size_t bytes) { char* p = W + off; off = (off + bytes + 255) & ~(size_t)255; return p; };
    _Float16* h_l16_0 = (_Float16*)alloc((size_t)NLIT * D * 2);
    _Float16* h_l16_1 = (_Float16*)alloc((size_t)NLIT * D * 2);
    _Float16* h_c16_0 = (_Float16*)alloc((size_t)NCLA * D * 2);
    _Float16* h_c16_1 = (_Float16*)alloc((size_t)NCLA * D * 2);
    _Float16* msg16   = (_Float16*)alloc((size_t)NLIT * D * 2);
    _Float16* c_l16   = (_Float16*)alloc((size_t)NLIT * D * 2);
    _Float16* c_c16   = (_Float16*)alloc((size_t)NCLA * D * 2);
    _Float16* Wc16    = (_Float16*)alloc(512 * 256 * 2);
    _Float16* Wl16    = (_Float16*)alloc(512 * 384 * 2);
    float*    bc      = (float*)  alloc(512 * 4);
    float*    bl      = (float*)  alloc(512 * 4);
    _Float16* hc0g    = (_Float16*)alloc(128 * 2);
    int* counts       = (int*)alloc((size_t)NLIT * 4);
    int* starts       = (int*)alloc((size_t)(NLIT + 1) * 4);
    int* cursor       = (int*)alloc((size_t)NLIT * 4);
    int* edge_clause  = (int*)alloc((size_t)NEDGE * 4);
    int* bsum         = (int*)alloc(128 * 4);
    int* ebsum        = (int*)alloc(128 * 4);

    float* out       = (float*)d_out;
    float* out_votes = out + BGR;
    float* out_hl    = out + BGR + NLIT;

    // counts must start at zero for the atomic histogram
    hipMemsetAsync(counts, 0, (size_t)NLIT * 4, stream);

    // ---- one-time conversions
    conv_x_kernel<<<(NLIT * 16 + 255) / 256, 256, 0, stream>>>(x_unk, h_l16_0);
    conv_wc_kernel<<<512, 256, 0, stream>>>(Wih_lc, Whh_lc, Wc16);
    conv_wl_kernel<<<512, 384, 0, stream>>>(Wih_cl, Whh_cl, Wl16);
    conv_bias_kernel<<<1, 512, 0, stream>>>(bih_lc, bhh_lc, bc, bih_cl, bhh_cl, bl,
                                            C_w, C_b, hc0g);

    // ---- CSR build (parallel scan)
    count_edges_kernel<<<(NEDGE + 255) / 256, 256, 0, stream>>>(lit_idx, counts);
    block_sum_kernel<<<NLIT / 256, 256, 0, stream>>>(counts, bsum);
    scan_bsum_kernel<<<1, 128, 0, stream>>>(bsum, ebsum, starts);
    scan_write_kernel<<<NLIT / 256, 256, 0, stream>>>(counts, ebsum, starts, cursor);
    fill_csr_kernel<<<(NEDGE + 255) / 256, 256, 0, stream>>>(lit_idx, clause_idx,
                                                             cursor, edge_clause);

    // ---- message-passing iterations (h_l and h_c ping-pong in f16)
    const _Float16* hl_old[ITERS] = {h_l16_0, h_l16_1, h_l16_0, h_l16_1};
    _Float16*       hl_new[ITERS] = {h_l16_1, h_l16_0, h_l16_1, h_l16_0};
    const _Float16* hc_old[ITERS] = {h_c16_0, h_c16_1, h_c16_0, h_c16_1};
    _Float16*       hc_new[ITERS] = {h_c16_1, h_c16_0, h_c16_1, h_c16_0};

    for (int it = 0; it < ITERS; ++it) {
        clause_mfma_kernel<<<(NCLA / 128) * 2, 256, 0, stream>>>(
            hl_old[it], hc_old[it], hc_new[it], c_c16, Wc16, bc, hc0g, lit_idx,
            it == 0 ? 1 : 0);
        gather_msg_kernel<<<(NLIT * 16 + 255) / 256, 256, 0, stream>>>(
            hc_new[it], msg16, starts, edge_clause);
        literal_mfma_kernel<<<(NLIT / 128) * 2, 256, 0, stream>>>(
            hl_old[it], msg16, hl_new[it],
            (it == ITERS - 1) ? out_hl : (float*)nullptr,
            c_l16, Wl16, bl, flip_perm,
            it == 0 ? 1 : 0);
    }

    votes_stage1_kernel<<<NLIT / 4, 256, 0, stream>>>(out_hl, out_w, out_b, out_votes);
    votes_stage2_kernel<<<BGR, 256, 0, stream>>>(out_votes, out);
}

// Round 8
// 531.184 us; speedup vs baseline: 1.9706x; 1.9706x over previous
//
#include <hip/hip_runtime.h>
#include <hip/hip_bf16.h>

// Problem constants (fixed by setup_inputs)
#define D     128
#define NLIT  32000
#define NCLA  64000
#define KLIT  3
#define NEDGE 192000
#define BGR   32
#define ITERS 4
#define LITS_PER_GRAPH 1000

typedef _Float16 f16x8 __attribute__((ext_vector_type(8)));
typedef float    f32x4 __attribute__((ext_vector_type(4)));

#define TSTRIDE 40   // LDS A-tile row stride in f16 (80 B): b128 reads at bank floor

__device__ __forceinline__ float sigf(float x)  { return 1.f / (1.f + __expf(-x)); }
__device__ __forceinline__ float tanhft(float x){ return 1.f - 2.f / (__expf(2.f * x) + 1.f); }

// ---------------------------------------------------------------------------
// one-time conversions
// ---------------------------------------------------------------------------
__global__ void conv_x_kernel(const float* __restrict__ x, _Float16* __restrict__ o) {
    int t = blockIdx.x * blockDim.x + threadIdx.x;          // NLIT*16
    if (t >= NLIT * 16) return;
    const float* p = x + t * 8;
    f16x8 v;
#pragma unroll
    for (int i = 0; i < 8; ++i) v[i] = (_Float16)p[i];
    *(f16x8*)((_Float16*)o + t * 8) = v;
}

// Wc: 512 x 256 f16  ([n][k], k<128 from Wih, else Whh)
__global__ void conv_wc_kernel(const float* __restrict__ Wih,
                               const float* __restrict__ Whh,
                               _Float16* __restrict__ Wc) {
    int n = blockIdx.x, k = threadIdx.x;                    // 512 x 256
    float v = (k < 128) ? Wih[n * 128 + k] : Whh[n * 128 + k - 128];
    Wc[n * 256 + k] = (_Float16)v;
}

// Wl: 512 x 384 f16  ([n][k], k<256 from Wih, else Whh)
__global__ void conv_wl_kernel(const float* __restrict__ Wih,
                               const float* __restrict__ Whh,
                               _Float16* __restrict__ Wl) {
    int n = blockIdx.x, k = threadIdx.x;                    // 512 x 384
    float v = (k < 256) ? Wih[n * 256 + k] : Whh[n * 128 + k - 256];
    Wl[n * 384 + k] = (_Float16)v;
}

// bias combine + hc0 (= C_w + C_b as f16, the iter-0 h_c broadcast row)
__global__ void conv_bias_kernel(const float* bih_c, const float* bhh_c, float* bc,
                                 const float* bih_l, const float* bhh_l, float* bl,
                                 const float* C_w, const float* C_b,
                                 _Float16* hc0g) {
    int t = threadIdx.x;                                    // 512
    bc[t] = bih_c[t] + bhh_c[t];
    bl[t] = bih_l[t] + bhh_l[t];
    if (t < 128) hc0g[t] = (_Float16)(C_w[t] + C_b[t]);
}

// ---------------------------------------------------------------------------
// CSR build: counts -> (block sums -> scan -> block-local scan) -> fill
// ---------------------------------------------------------------------------
__global__ void count_edges_kernel(const int* __restrict__ lit_idx,
                                   int* __restrict__ counts) {
    int e = blockIdx.x * blockDim.x + threadIdx.x;
    if (e < NEDGE) atomicAdd(&counts[lit_idx[e]], 1);
}

__global__ __launch_bounds__(256)
void block_sum_kernel(const int* __restrict__ counts, int* __restrict__ bsum) {
    int b = blockIdx.x, t = threadIdx.x;
    int v = counts[b * 256 + t];
    int lane = t & 63, w = t >> 6;
#pragma unroll
    for (int off = 32; off > 0; off >>= 1) v += __shfl_down(v, off, 64);
    __shared__ int ws[4];
    if (lane == 0) ws[w] = v;
    __syncthreads();
    if (t == 0) bsum[b] = ws[0] + ws[1] + ws[2] + ws[3];
}

__global__ void scan_bsum_kernel(const int* __restrict__ bsum,
                                 int* __restrict__ ebsum,
                                 int* __restrict__ starts) {
    __shared__ int s[128];
    int t = threadIdx.x;
    int v = (t < 125) ? bsum[t] : 0;
    s[t] = v;
    __syncthreads();
    for (int off = 1; off < 128; off <<= 1) {
        int y = (t >= off) ? s[t - off] : 0;
        __syncthreads();
        s[t] += y;
        __syncthreads();
    }
    if (t < 125) ebsum[t] = s[t] - v;       // exclusive
    if (t == 0) starts[NLIT] = NEDGE;
}

__global__ __launch_bounds__(256)
void scan_write_kernel(const int* __restrict__ counts,
                       const int* __restrict__ ebsum,
                       int* __restrict__ starts,
                       int* __restrict__ cursor) {
    int b = blockIdx.x, t = threadIdx.x;
    int idx = b * 256 + t;
    int v = counts[idx];
    int lane = t & 63, w = t >> 6;
    int x = v;
#pragma unroll
    for (int off = 1; off < 64; off <<= 1) {
        int y = __shfl_up(x, off, 64);
        if (lane >= off) x += y;
    }
    __shared__ int wsum[4];
    if (lane == 63) wsum[w] = x;
    __syncthreads();
    int woff = 0;
#pragma unroll
    for (int i = 0; i < 4; ++i) if (i < w) woff += wsum[i];
    int g = ebsum[b] + woff + x - v;        // exclusive prefix
    starts[idx] = g;
    cursor[idx] = g;
}

__global__ void fill_csr_kernel(const int* __restrict__ lit_idx,
                                const int* __restrict__ clause_idx,
                                int* __restrict__ cursor,
                                int* __restrict__ edge_clause) {
    int e = blockIdx.x * blockDim.x + threadIdx.x;
    if (e < NEDGE) {
        int l = lit_idx[e];
        int pos = atomicAdd(&cursor[l], 1);
        edge_clause[pos] = clause_idx[e];
    }
}

// ---------------------------------------------------------------------------
// msg_l[l][:] = sum over clauses of literal l of h_c16[clause][:]  (f16 io, fp32 acc)
// high-occupancy streaming gather (separate kernel — round-5 fusion regressed)
// ---------------------------------------------------------------------------
__global__ void gather_msg_kernel(const _Float16* __restrict__ h_c16,
                                  _Float16* __restrict__ msg16,
                                  const int* __restrict__ starts,
                                  const int* __restrict__ edge_clause) {
    int t = blockIdx.x * blockDim.x + threadIdx.x;          // NLIT*16
    if (t >= NLIT * 16) return;
    int l = t >> 4;
    int off = (t & 15) * 8;
    int s = starts[l], e = starts[l + 1];
    float a[8];
#pragma unroll
    for (int i = 0; i < 8; ++i) a[i] = 0.f;
    for (int j = s; j < e; ++j) {
        f16x8 v = *(const f16x8*)&h_c16[(size_t)edge_clause[j] * D + off];
#pragma unroll
        for (int i = 0; i < 8; ++i) a[i] += (float)v[i];
    }
    f16x8 o;
#pragma unroll
    for (int i = 0; i < 8; ++i) o[i] = (_Float16)a[i];
    *(f16x8*)&msg16[(size_t)l * D + off] = o;
}

// ---------------------------------------------------------------------------
// Clause LSTM (MFMA): 128 rows/block, d-half per block (c = bx&1).
// A = [gather3(h_l) | h_c_old], K=256.
// A staged through DOUBLE-BUFFERED LDS (one barrier/chunk); B fragments
// loaded directly from global into registers (no cross-wave reuse).
// __launch_bounds__(256,2): acc(128 unified regs) must NOT spill (r7 lesson).
// ---------------------------------------------------------------------------
__global__ __launch_bounds__(256, 2)
void clause_mfma_kernel(const _Float16* __restrict__ h_l16,   // NLIT x 128
                        const _Float16* __restrict__ h_c_old, // NCLA x 128
                        _Float16* __restrict__ h_c_new,       // NCLA x 128
                        _Float16* __restrict__ c_c16,         // NCLA x 128 (f16 cell)
                        const _Float16* __restrict__ Wc,      // 512 x 256
                        const float* __restrict__ bc,         // 512
                        const _Float16* __restrict__ hc0g,    // 128 (iter-0 h_c row)
                        const int* __restrict__ lit_idx,
                        int first) {
    __shared__ _Float16 At[2][128 * TSTRIDE];
    __shared__ int      lidx[384];

    const int tid  = threadIdx.x;
    const int w    = tid >> 6;
    const int lane = tid & 63;
    const int qd   = lane >> 4;
    const int ln   = lane & 15;
    const int c    = blockIdx.x & 1;             // d-half: cols [64c, 64c+64)
    const int row0 = (blockIdx.x >> 1) * 128;

    for (int i = tid; i < 384; i += 256) lidx[i] = lit_idx[row0 * 3 + i];
    __syncthreads();                             // lidx visible before prefetch

    const int nrow = c * 64 + 16 * w + ln;       // W row base for this lane's col
    const int koff = qd * 8;                     // lane's k-granule inside chunk

    f16x8 ldB[4];    // B prefetch (direct global, per-gate)
    f16x8 ldG[2][3]; // A prefetch (ch<4: 3-lit gather; ch>=4: ldG[s2][0] = copy)

    // ---- prefetch ch 0
#pragma unroll
    for (int g = 0; g < 4; ++g)
        ldB[g] = *(const f16x8*)&Wc[(size_t)(g * 128 + nrow) * 256 + koff];
#pragma unroll
    for (int s2 = 0; s2 < 2; ++s2) {
        int s = tid + 256 * s2;
        int m = s >> 2, col8 = (s & 3) * 8;
#pragma unroll
        for (int r = 0; r < 3; ++r)
            ldG[s2][r] = *(const f16x8*)&h_l16[(size_t)lidx[3 * m + r] * D + col8];
    }

    f32x4 acc[8][4];
#pragma unroll
    for (int R = 0; R < 8; ++R)
#pragma unroll
        for (int g = 0; g < 4; ++g) { acc[R][g][0]=0.f; acc[R][g][1]=0.f; acc[R][g][2]=0.f; acc[R][g][3]=0.f; }

    for (int ch = 0; ch < 8; ++ch) {
        _Float16* buf = (_Float16*)At[ch & 1];
        // ---- A tile (chunk ch, already in regs) -> LDS buffer ch&1.
        // Safe without a pre-store barrier: reads of this buffer (chunk ch-2)
        // completed before barrier ch-1, which precedes this store.
#pragma unroll
        for (int s2 = 0; s2 < 2; ++s2) {
            int s = tid + 256 * s2;
            int m = s >> 2, col8 = (s & 3) * 8;
            if (ch < 4) {
                f16x8 o;
#pragma unroll
                for (int e = 0; e < 8; ++e)
                    o[e] = (_Float16)((float)ldG[s2][0][e] + (float)ldG[s2][1][e] + (float)ldG[s2][2][e]);
                *(f16x8*)&buf[m * TSTRIDE + col8] = o;
            } else {
                *(f16x8*)&buf[m * TSTRIDE + col8] = ldG[s2][0];
            }
        }
        // ---- current-chunk B fragments (already in regs)
        f16x8 bf[4];
#pragma unroll
        for (int g = 0; g < 4; ++g) bf[g] = ldB[g];
        // ---- prefetch ch+1 (latency overlapped with MFMA below)
        if (ch < 7) {
            const int k0n = (ch + 1) * 32;
#pragma unroll
            for (int g = 0; g < 4; ++g)
                ldB[g] = *(const f16x8*)&Wc[(size_t)(g * 128 + nrow) * 256 + k0n + koff];
            if (ch + 1 < 4) {
#pragma unroll
                for (int s2 = 0; s2 < 2; ++s2) {
                    int s = tid + 256 * s2;
                    int m = s >> 2, col8 = (s & 3) * 8;
#pragma unroll
                    for (int r = 0; r < 3; ++r)
                        ldG[s2][r] = *(const f16x8*)&h_l16[(size_t)lidx[3 * m + r] * D + k0n + col8];
                }
            } else {
                const int kk = k0n - 128;
#pragma unroll
                for (int s2 = 0; s2 < 2; ++s2) {
                    int s = tid + 256 * s2;
                    int m = s >> 2, col8 = (s & 3) * 8;
                    ldG[s2][0] = first ? *(const f16x8*)&hc0g[kk + col8]
                                       : *(const f16x8*)&h_c_old[(size_t)(row0 + m) * D + kk + col8];
                }
            }
        }
        __syncthreads();                 // tile ch stored by all waves
        // ---- fragments + MFMA
        f16x8 af[8];
#pragma unroll
        for (int R = 0; R < 8; ++R)
            af[R] = *(const f16x8*)&buf[(16 * R + ln) * TSTRIDE + koff];
#pragma unroll
        for (int R = 0; R < 8; ++R)
#pragma unroll
            for (int g = 0; g < 4; ++g)
                acc[R][g] = __builtin_amdgcn_mfma_f32_16x16x32_f16(af[R], bf[g], acc[R][g], 0, 0, 0);
    }

    // ---- fused LSTM epilogue (full i,f,g,o quadruple in registers; f16 cell)
    const int dcol = c * 64 + 16 * w + ln;     // 0..127
    const float b0 = bc[dcol], b1 = bc[128 + dcol], b2 = bc[256 + dcol], b3 = bc[384 + dcol];
#pragma unroll
    for (int R = 0; R < 8; ++R) {
#pragma unroll
        for (int r = 0; r < 4; ++r) {
            int m = row0 + 16 * R + qd * 4 + r;
            size_t idx = (size_t)m * D + dcol;
            float gi = acc[R][0][r] + b0;
            float gf = acc[R][1][r] + b1;
            float gg = acc[R][2][r] + b2;
            float go = acc[R][3][r] + b3;
            float cn = sigf(gi) * tanhft(gg);
            if (!first) cn += sigf(gf) * (float)c_c16[idx];
            float h  = sigf(go) * tanhft(cn);
            c_c16[idx]   = (_Float16)cn;
            h_c_new[idx] = (_Float16)h;
        }
    }
}

// ---------------------------------------------------------------------------
// Literal LSTM (MFMA): A = [msg_l | h_old[flip] | h_old], K=384, 128 rows/block.
// Same structure: double-buffered LDS A, B direct-global, one barrier/chunk.
// ---------------------------------------------------------------------------
__global__ __launch_bounds__(256, 2)
void literal_mfma_kernel(const _Float16* __restrict__ h_old16, // NLIT x 128
                         const _Float16* __restrict__ msg16,   // NLIT x 128
                         _Float16* __restrict__ h_new16,       // NLIT x 128
                         float* __restrict__ h32,              // fp32 out (final iter)
                         _Float16* __restrict__ c_l16,         // NLIT x 128 (f16 cell)
                         const _Float16* __restrict__ Wl384,   // 512 x 384
                         const float* __restrict__ bl,         // 512
                         const int* __restrict__ flip_perm,
                         int first) {
    __shared__ _Float16 At[2][128 * TSTRIDE];
    __shared__ int      flip_s[128];

    const int tid  = threadIdx.x;
    const int w    = tid >> 6;
    const int lane = tid & 63;
    const int qd   = lane >> 4;
    const int ln   = lane & 15;
    const int c    = blockIdx.x & 1;
    const int row0 = (blockIdx.x >> 1) * 128;

    if (tid < 128) flip_s[tid] = flip_perm[row0 + tid];
    __syncthreads();

    const int nrow = c * 64 + 16 * w + ln;
    const int koff = qd * 8;

    f16x8 ldB[4];
    f16x8 ldA[2];

    // ---- prefetch ch 0 (msg)
#pragma unroll
    for (int g = 0; g < 4; ++g)
        ldB[g] = *(const f16x8*)&Wl384[(size_t)(g * 128 + nrow) * 384 + koff];
#pragma unroll
    for (int s2 = 0; s2 < 2; ++s2) {
        int s = tid + 256 * s2;
        int m = s >> 2, col8 = (s & 3) * 8;
        ldA[s2] = *(const f16x8*)&msg16[(size_t)(row0 + m) * D + col8];
    }

    f32x4 acc[8][4];
#pragma unroll
    for (int R = 0; R < 8; ++R)
#pragma unroll
        for (int g = 0; g < 4; ++g) { acc[R][g][0]=0.f; acc[R][g][1]=0.f; acc[R][g][2]=0.f; acc[R][g][3]=0.f; }

    for (int ch = 0; ch < 12; ++ch) {
        _Float16* buf = (_Float16*)At[ch & 1];
        // ---- A tile to LDS (double-buffered)
#pragma unroll
        for (int s2 = 0; s2 < 2; ++s2) {
            int s = tid + 256 * s2;
            int m = s >> 2, col8 = (s & 3) * 8;
            *(f16x8*)&buf[m * TSTRIDE + col8] = ldA[s2];
        }
        // ---- current-chunk B fragments
        f16x8 bf[4];
#pragma unroll
        for (int g = 0; g < 4; ++g) bf[g] = ldB[g];
        // ---- prefetch ch+1
        if (ch < 11) {
            const int k0n = (ch + 1) * 32;
#pragma unroll
            for (int g = 0; g < 4; ++g)
                ldB[g] = *(const f16x8*)&Wl384[(size_t)(g * 128 + nrow) * 384 + k0n + koff];
#pragma unroll
            for (int s2 = 0; s2 < 2; ++s2) {
                int s = tid + 256 * s2;
                int m = s >> 2, col8 = (s & 3) * 8;
                const _Float16* g;
                if (k0n < 128)      g = msg16   + (size_t)(row0 + m) * D + k0n + col8;
                else if (k0n < 256) g = h_old16 + (size_t)flip_s[m] * D + (k0n - 128) + col8;
                else                g = h_old16 + (size_t)(row0 + m) * D + (k0n - 256) + col8;
                ldA[s2] = *(const f16x8*)g;
            }
        }
        __syncthreads();
        // ---- fragments + MFMA
        f16x8 af[8];
#pragma unroll
        for (int R = 0; R < 8; ++R)
            af[R] = *(const f16x8*)&buf[(16 * R + ln) * TSTRIDE + koff];
#pragma unroll
        for (int R = 0; R < 8; ++R)
#pragma unroll
            for (int g = 0; g < 4; ++g)
                acc[R][g] = __builtin_amdgcn_mfma_f32_16x16x32_f16(af[R], bf[g], acc[R][g], 0, 0, 0);
    }

    const int dcol = c * 64 + 16 * w + ln;
    const float b0 = bl[dcol], b1 = bl[128 + dcol], b2 = bl[256 + dcol], b3 = bl[384 + dcol];
#pragma unroll
    for (int R = 0; R < 8; ++R) {
#pragma unroll
        for (int r = 0; r < 4; ++r) {
            int m = row0 + 16 * R + qd * 4 + r;
            size_t idx = (size_t)m * D + dcol;
            float gi = acc[R][0][r] + b0;
            float gf = acc[R][1][r] + b1;
            float gg = acc[R][2][r] + b2;
            float go = acc[R][3][r] + b3;
            float cn = sigf(gi) * tanhft(gg);
            if (!first) cn += sigf(gf) * (float)c_l16[idx];
            float h  = sigf(go) * tanhft(cn);
            c_l16[idx]   = (_Float16)cn;
            h_new16[idx] = (_Float16)h;
            if (h32) h32[idx] = h;
        }
    }
}

// ---------------------------------------------------------------------------
// votes stage 1: one wave per literal, no atomics.
// ---------------------------------------------------------------------------
__global__ __launch_bounds__(256)
void votes_stage1_kernel(const float* __restrict__ h_l,
                         const float* __restrict__ out_w,
                         const float* __restrict__ out_b,
                         float* __restrict__ votes_out) {
    int w    = threadIdx.x >> 6;            // wave in block
    int lane = threadIdx.x & 63;
    int l    = blockIdx.x * 4 + w;          // grid = NLIT/4
    if (l >= NLIT) return;
    const float2 v = *(const float2*)&h_l[(size_t)l * D + lane * 2];
    const float2 ww = *(const float2*)&out_w[lane * 2];
    float p = v.x * ww.x + v.y * ww.y;
#pragma unroll
    for (int off = 32; off > 0; off >>= 1) p += __shfl_down(p, off, 64);
    if (lane == 0) votes_out[l] = p + out_b[0];
}

// votes stage 2: one block per graph, sum 1000 contiguous votes -> mean
__global__ __launch_bounds__(256)
void votes_stage2_kernel(const float* __restrict__ votes,
                         float* __restrict__ out0) {
    int b = blockIdx.x;                     // 32 graphs
    int t = threadIdx.x;
    const float* base = votes + (size_t)b * LITS_PER_GRAPH;
    float s = 0.f;
    for (int i = t; i < LITS_PER_GRAPH; i += 256) s += base[i];
#pragma unroll
    for (int off = 32; off > 0; off >>= 1) s += __shfl_down(s, off, 64);
    __shared__ float ws[4];
    if ((t & 63) == 0) ws[t >> 6] = s;
    __syncthreads();
    if (t == 0) out0[b] = (ws[0] + ws[1] + ws[2] + ws[3]) / (float)LITS_PER_GRAPH;
}

// ---------------------------------------------------------------------------
extern "C" void kernel_launch(void* const* d_in, const int* in_sizes, int n_in,
                              void* d_out, int out_size, void* d_ws, size_t ws_size,
                              hipStream_t stream) {
    (void)in_sizes; (void)n_in; (void)out_size; (void)ws_size;

    const float* x_unk  = (const float*)d_in[0];
    const float* C_w    = (const float*)d_in[1];
    const float* C_b    = (const float*)d_in[2];
    const float* Wih_lc = (const float*)d_in[3];
    const float* Whh_lc = (const float*)d_in[4];
    const float* bih_lc = (const float*)d_in[5];
    const float* bhh_lc = (const float*)d_in[6];
    const float* Wih_cl = (const float*)d_in[7];
    const float* Whh_cl = (const float*)d_in[8];
    const float* bih_cl = (const float*)d_in[9];
    const float* bhh_cl = (const float*)d_in[10];
    const float* out_w  = (const float*)d_in[11];
    const float* out_b  = (const float*)d_in[12];
    const int* lit_idx    = (const int*)d_in[13];
    const int* clause_idx = (const int*)d_in[14];
    const int* flip_perm  = (const int*)d_in[16];

    // ---- workspace layout (bytes, 256-aligned chunks)
    char* W = (char*)d_ws;
    size_t off = 0;
    auto alloc = [&](size_t bytes) { char* p = W + off; off = (off + bytes + 255) & ~(size_t)255; return p; };
    _Float16* h_l16_0 = (_Float16*)alloc((size_t)NLIT * D * 2);
    _Float16* h_l16_1 = (_Float16*)alloc((size_t)NLIT * D * 2);
    _Float16* h_c16_0 = (_Float16*)alloc((size_t)NCLA * D * 2);
    _Float16* h_c16_1 = (_Float16*)alloc((size_t)NCLA * D * 2);
    _Float16* msg16   = (_Float16*)alloc((size_t)NLIT * D * 2);
    _Float16* c_l16   = (_Float16*)alloc((size_t)NLIT * D * 2);
    _Float16* c_c16   = (_Float16*)alloc((size_t)NCLA * D * 2);
    _Float16* Wc16    = (_Float16*)alloc(512 * 256 * 2);
    _Float16* Wl16    = (_Float16*)alloc(512 * 384 * 2);
    float*    bc      = (float*)  alloc(512 * 4);
    float*    bl      = (float*)  alloc(512 * 4);
    _Float16* hc0g    = (_Float16*)alloc(128 * 2);
    int* counts       = (int*)alloc((size_t)NLIT * 4);
    int* starts       = (int*)alloc((size_t)(NLIT + 1) * 4);
    int* cursor       = (int*)alloc((size_t)NLIT * 4);
    int* edge_clause  = (int*)alloc((size_t)NEDGE * 4);
    int* bsum         = (int*)alloc(128 * 4);
    int* ebsum        = (int*)alloc(128 * 4);

    float* out       = (float*)d_out;
    float* out_votes = out + BGR;
    float* out_hl    = out + BGR + NLIT;

    // counts must start at zero for the atomic histogram
    hipMemsetAsync(counts, 0, (size_t)NLIT * 4, stream);

    // ---- one-time conversions
    conv_x_kernel<<<(NLIT * 16 + 255) / 256, 256, 0, stream>>>(x_unk, h_l16_0);
    conv_wc_kernel<<<512, 256, 0, stream>>>(Wih_lc, Whh_lc, Wc16);
    conv_wl_kernel<<<512, 384, 0, stream>>>(Wih_cl, Whh_cl, Wl16);
    conv_bias_kernel<<<1, 512, 0, stream>>>(bih_lc, bhh_lc, bc, bih_cl, bhh_cl, bl,
                                            C_w, C_b, hc0g);

    // ---- CSR build (parallel scan)
    count_edges_kernel<<<(NEDGE + 255) / 256, 256, 0, stream>>>(lit_idx, counts);
    block_sum_kernel<<<NLIT / 256, 256, 0, stream>>>(counts, bsum);
    scan_bsum_kernel<<<1, 128, 0, stream>>>(bsum, ebsum, starts);
    scan_write_kernel<<<NLIT / 256, 256, 0, stream>>>(counts, ebsum, starts, cursor);
    fill_csr_kernel<<<(NEDGE + 255) / 256, 256, 0, stream>>>(lit_idx, clause_idx,
                                                             cursor, edge_clause);

    // ---- message-passing iterations (h_l and h_c ping-pong in f16)
    const _Float16* hl_old[ITERS] = {h_l16_0, h_l16_1, h_l16_0, h_l16_1};
    _Float16*       hl_new[ITERS] = {h_l16_1, h_l16_0, h_l16_1, h_l16_0};
    const _Float16* hc_old[ITERS] = {h_c16_0, h_c16_1, h_c16_0, h_c16_1};
    _Float16*       hc_new[ITERS] = {h_c16_1, h_c16_0, h_c16_1, h_c16_0};

    for (int it = 0; it < ITERS; ++it) {
        clause_mfma_kernel<<<(NCLA / 128) * 2, 256, 0, stream>>>(
            hl_old[it], hc_old[it], hc_new[it], c_c16, Wc16, bc, hc0g, lit_idx,
            it == 0 ? 1 : 0);
        gather_msg_kernel<<<(NLIT * 16 + 255) / 256, 256, 0, stream>>>(
            hc_new[it], msg16, starts, edge_clause);
        literal_mfma_kernel<<<(NLIT / 128) * 2, 256, 0, stream>>>(
            hl_old[it], msg16, hl_new[it],
            (it == ITERS - 1) ? out_hl : (float*)nullptr,
            c_l16, Wl16, bl, flip_perm,
            it == 0 ? 1 : 0);
    }

    votes_stage1_kernel<<<NLIT / 4, 256, 0, stream>>>(out_hl, out_w, out_b, out_votes);
    votes_stage2_kernel<<<BGR, 256, 0, stream>>>(out_votes, out);
}